// Round 1
// baseline (153.810 us; speedup 1.0000x reference)
//
#include <hip/hip_runtime.h>
#include <math.h>

#define Bv 256
#define Tv 16
#define Fv 8
#define Dv 32
#define Kv 64
#define Cv 1024
#define Ov 2
#define D1 33   // D+1

typedef unsigned long long u64;

// ---------------------------------------------------------------------------
// Kernel 1: per (f,c) — pack pattern bytes + wildcard mask; precompute
//   kk[f,c,i] = sum_j Wk[f,i,j]*rep[f,c,j] + bk[f,i]   (i<32, j<33)
//   vv[f,c,i] = sum_j Wv[f,i,j]*rep[f,c,j] + bv[f,i]   (i<33)
// where rep = concat(pat_rep, pos/(pos+neg+1e-6)).
// ---------------------------------------------------------------------------
__global__ __launch_bounds__(64) void prep_kernel(
    const int* __restrict__ pat, const float* __restrict__ pat_rep,
    const float* __restrict__ pos_cnt, const float* __restrict__ neg_cnt,
    const float* __restrict__ W_k, const float* __restrict__ b_k,
    const float* __restrict__ W_v, const float* __restrict__ b_v,
    u64* __restrict__ pat64, u64* __restrict__ care64,
    float* __restrict__ kk, float* __restrict__ vv) {
  int fc = blockIdx.x;          // f*Cv + c
  int f = fc >> 10;
  int tid = threadIdx.x;
  __shared__ float rep[D1];
  if (tid < Dv) rep[tid] = pat_rep[fc * Dv + tid];
  if (tid == Dv) {
    float p = pos_cnt[fc], n = neg_cnt[fc];
    rep[Dv] = p / (p + n + 1e-6f);
  }
  if (tid == 63) {
    u64 pp = 0, cm = 0;
    const int* prow = pat + fc * Fv;
    #pragma unroll
    for (int ff = 0; ff < Fv; ff++) {
      int pv = prow[ff];
      pp |= ((u64)(pv & 0xFF)) << (8 * ff);
      if (pv != 0) cm |= 0xFFull << (8 * ff);
    }
    pat64[fc] = pp;
    care64[fc] = cm;
  }
  __syncthreads();
  if (tid < Dv) {
    const float* w = W_k + (f * Dv + tid) * D1;
    float s = b_k[f * Dv + tid];
    #pragma unroll
    for (int j = 0; j < D1; j++) s += w[j] * rep[j];
    kk[fc * Dv + tid] = s;
  }
  if (tid < D1) {
    const float* w = W_v + (f * D1 + tid) * D1;
    float s = b_v[f * D1 + tid];
    #pragma unroll
    for (int j = 0; j < D1; j++) s += w[j] * rep[j];
    vv[fc * D1 + tid] = s;
  }
}

// ---------------------------------------------------------------------------
// Kernel 2: per (b,t) — VQ code per feature (argmin over 64 centers, first-
// index tiebreak, matching jnp.argmin), masked -> byte-packed u64.
// One wave (64 lanes) per (b,t); lane = center index.
// ---------------------------------------------------------------------------
__global__ __launch_bounds__(64) void codes_kernel(
    const float* __restrict__ tdata, const int* __restrict__ f_mask,
    const float* __restrict__ centers, u64* __restrict__ code64) {
  int bt = blockIdx.x;          // b*Tv + t
  int lane = threadIdx.x;       // center k
  __shared__ float xs[Dv];
  u64 code = 0;
  for (int ff = 0; ff < Fv; ff++) {
    if (lane < Dv) xs[lane] = tdata[(bt * Fv + ff) * Dv + lane];
    __syncthreads();
    float xx = 0.0f;
    #pragma unroll
    for (int j = 0; j < Dv; j++) xx += xs[j] * xs[j];
    const float* cen = centers + (ff * Kv + lane) * Dv;
    float dot = 0.0f, cc = 0.0f;
    #pragma unroll
    for (int j = 0; j < Dv; j++) { float cv = cen[j]; dot += xs[j] * cv; cc += cv * cv; }
    float d = xx - 2.0f * dot + cc;
    int kidx = lane;
    #pragma unroll
    for (int off = 32; off >= 1; off >>= 1) {
      float od = __shfl_xor(d, off, 64);
      int ok = __shfl_xor(kidx, off, 64);
      if (od < d || (od == d && ok < kidx)) { d = od; kidx = ok; }
    }
    int m = f_mask[bt * Fv + ff];
    int codev = (m != 0) ? (kidx + 2) : 1;
    code |= ((u64)codev) << (8 * ff);
    __syncthreads();
  }
  if (lane == 0) code64[bt] = code;
}

// ---------------------------------------------------------------------------
// Kernel 3: per (f,b) block — match scan, softmax, a_all write, sparse PV.
// 256 threads, 4 patterns per thread.
// ---------------------------------------------------------------------------
__global__ __launch_bounds__(256) void attn_kernel(
    const float* __restrict__ tdata, const int* __restrict__ f_mask,
    const float* __restrict__ W_q, const float* __restrict__ b_q,
    const float* __restrict__ b_v,
    const u64* __restrict__ code64, const u64* __restrict__ pat64,
    const u64* __restrict__ care64,
    const float* __restrict__ kk, const float* __restrict__ vv,
    float* __restrict__ a_out, float* __restrict__ srep_out) {
  int b = blockIdx.x, f = blockIdx.y;
  int tid = threadIdx.x;
  __shared__ float qs[Dv], iqs[Dv];
  __shared__ u64 cds[Tv];
  __shared__ float redm[4], reds[4];
  __shared__ float vsum[D1];
  __shared__ int fm_sh;

  if (tid < Tv) cds[tid] = code64[b * Tv + tid];
  if (tid < Dv) qs[tid] = tdata[((b * Tv + (Tv - 1)) * Fv + f) * Dv + tid];
  if (tid < D1) vsum[tid] = 0.0f;
  if (tid == 64) {
    int any = 0;
    #pragma unroll
    for (int t = 0; t < Tv; t++) any |= f_mask[(b * Tv + t) * Fv + f];
    fm_sh = (any != 0);
  }
  __syncthreads();
  if (tid < Dv) {
    const float* w = W_q + (f * Dv + tid) * Dv;
    float s = b_q[f * Dv + tid];
    #pragma unroll
    for (int j = 0; j < Dv; j++) s += w[j] * qs[j];
    iqs[tid] = s;
  }
  __syncthreads();

  int c0 = tid * 4;
  const u64* p64 = pat64 + f * Cv;
  const u64* c64 = care64 + f * Cv;
  bool matchv[4];
  float ev[4];
  float local_max = -INFINITY;
  #pragma unroll
  for (int j = 0; j < 4; j++) {
    int c = c0 + j;
    u64 pp = p64[c], cm = c64[c];
    bool m = false;
    #pragma unroll
    for (int t = 0; t < Tv; t++) m = m || (((cds[t] ^ pp) & cm) == 0ull);
    matchv[j] = m;
    ev[j] = 0.0f;
    if (m) {
      const float* krow = kk + (f * Cv + c) * Dv;
      float s = 0.0f;
      #pragma unroll
      for (int jj = 0; jj < Dv; jj++) s += krow[jj] * iqs[jj];
      ev[j] = s;
      local_max = fmaxf(local_max, s);
    }
  }

  // block max of matched e (stays -inf if no match in whole block)
  float mx = local_max;
  #pragma unroll
  for (int off = 32; off >= 1; off >>= 1) mx = fmaxf(mx, __shfl_xor(mx, off, 64));
  if ((tid & 63) == 0) redm[tid >> 6] = mx;
  __syncthreads();
  float bmax = fmaxf(fmaxf(redm[0], redm[1]), fmaxf(redm[2], redm[3]));
  bool nomatch = (bmax == -INFINITY);

  float av[4] = {0.f, 0.f, 0.f, 0.f};
  float lsum = 0.0f;
  if (!nomatch) {
    #pragma unroll
    for (int j = 0; j < 4; j++) {
      if (matchv[j]) { av[j] = expf(ev[j] - bmax); lsum += av[j]; }
    }
  }
  float ss = lsum;
  #pragma unroll
  for (int off = 32; off >= 1; off >>= 1) ss += __shfl_xor(ss, off, 64);
  if ((tid & 63) == 0) reds[tid >> 6] = ss;
  __syncthreads();
  float Z = reds[0] + reds[1] + reds[2] + reds[3];

  float4 aq;
  if (nomatch) {
    const float u = 1.0f / 1024.0f;
    aq = make_float4(u, u, u, u);
  } else {
    float a0 = av[0] / Z, a1 = av[1] / Z, a2 = av[2] / Z, a3 = av[3] / Z;
    aq = make_float4(a0, a1, a2, a3);
    // sparse PV accumulation (a is exactly 0 for unmatched)
    float aa[4] = {a0, a1, a2, a3};
    #pragma unroll
    for (int j = 0; j < 4; j++) {
      if (matchv[j] && aa[j] != 0.0f) {
        const float* vrow = vv + (f * Cv + c0 + j) * D1;
        for (int d = 0; d < D1; d++) atomicAdd(&vsum[d], aa[j] * vrow[d]);
      }
    }
  }
  // a_all write: row (f,b), contiguous 1024 floats, float4 per thread
  ((float4*)(a_out + (size_t)(f * Bv + b) * Cv))[tid] = aq;

  __syncthreads();
  if (tid < D1) {
    float vd = nomatch ? b_v[f * D1 + tid] : vsum[tid];
    srep_out[(b * Fv + f) * D1 + tid] = fm_sh ? vd : 0.0f;
  }
}

// ---------------------------------------------------------------------------
// Kernel 4: cali[b,o] = srep[b,:] . W_pred[o,:]
// ---------------------------------------------------------------------------
__global__ __launch_bounds__(256) void cali_kernel(
    const float* __restrict__ srep, const float* __restrict__ W_pred,
    float* __restrict__ cali) {
  int i = blockIdx.x * blockDim.x + threadIdx.x;   // b*Ov + o
  if (i >= Bv * Ov) return;
  int b = i >> 1, o = i & 1;
  const float* s = srep + b * (Fv * D1);
  const float* w = W_pred + o * (Fv * D1);
  float acc = 0.0f;
  #pragma unroll 8
  for (int j = 0; j < Fv * D1; j++) acc += s[j] * w[j];
  cali[i] = acc;
}

extern "C" void kernel_launch(void* const* d_in, const int* in_sizes, int n_in,
                              void* d_out, int out_size, void* d_ws, size_t ws_size,
                              hipStream_t stream) {
  const float* tdata   = (const float*)d_in[0];
  const int*   f_mask  = (const int*)d_in[1];
  const float* centers = (const float*)d_in[2];
  const int*   pat     = (const int*)d_in[3];
  const float* pat_rep = (const float*)d_in[4];
  const float* pos_cnt = (const float*)d_in[5];
  const float* neg_cnt = (const float*)d_in[6];
  const float* W_q     = (const float*)d_in[7];
  const float* b_q     = (const float*)d_in[8];
  const float* W_k     = (const float*)d_in[9];
  const float* b_k     = (const float*)d_in[10];
  const float* W_v     = (const float*)d_in[11];
  const float* b_v     = (const float*)d_in[12];
  const float* W_pred  = (const float*)d_in[13];

  float* out = (float*)d_out;
  float* cali = out;                                        // Bv*Ov
  float* a_all = out + (Bv * Ov);                           // Fv*Bv*Cv
  float* srep = out + (Bv * Ov) + (Fv * (size_t)Bv * Cv);   // Bv*Fv*D1

  char* ws = (char*)d_ws;
  u64*   code64 = (u64*)(ws);                               // Bv*Tv
  u64*   pat64  = (u64*)(ws + 32768);                       // Fv*Cv
  u64*   care64 = (u64*)(ws + 98304);                       // Fv*Cv
  float* kk     = (float*)(ws + 163840);                    // Fv*Cv*Dv
  float* vv     = (float*)(ws + 163840 + Fv * Cv * Dv * 4); // Fv*Cv*D1

  prep_kernel<<<Fv * Cv, 64, 0, stream>>>(pat, pat_rep, pos_cnt, neg_cnt,
                                          W_k, b_k, W_v, b_v,
                                          pat64, care64, kk, vv);
  codes_kernel<<<Bv * Tv, 64, 0, stream>>>(tdata, f_mask, centers, code64);
  attn_kernel<<<dim3(Bv, Fv), 256, 0, stream>>>(tdata, f_mask, W_q, b_q, b_v,
                                                code64, pat64, care64, kk, vv,
                                                a_all, srep);
  cali_kernel<<<(Bv * Ov + 255) / 256, 256, 0, stream>>>(srep, W_pred, cali);
}

// Round 2
// 140.918 us; speedup vs baseline: 1.0915x; 1.0915x over previous
//
#include <hip/hip_runtime.h>
#include <math.h>

#define Bv 256
#define Tv 16
#define Fv 8
#define Dv 32
#define Kv 64
#define Cv 1024
#define Ov 2
#define D1 33   // D+1

typedef unsigned long long u64;

// ---------------------------------------------------------------------------
// K1: fused prep (blocks [0,8192)) + codes (blocks [8192,12288)) + cali zero
// (block 12288). 64 threads per block.
// prep per (f,c): pack pattern bytes + care mask; precompute
//   kk[f,c,i] = sum_j Wk[f,i,j]*rep[f,c,j] + bk[f,i]   (i<32, j<33)
//   vv[f,c,i] = sum_j Wv[f,i,j]*rep[f,c,j] + bv[f,i]   (i<33)
// codes per (b,t): argmin over 64 centers per feature (lane = center,
// first-index tiebreak matching jnp.argmin), masked, byte-packed u64.
// ---------------------------------------------------------------------------
__global__ __launch_bounds__(64) void k1_prep_codes(
    const int* __restrict__ pat, const float* __restrict__ pat_rep,
    const float* __restrict__ pos_cnt, const float* __restrict__ neg_cnt,
    const float* __restrict__ W_k, const float* __restrict__ b_k,
    const float* __restrict__ W_v, const float* __restrict__ b_v,
    const float* __restrict__ tdata, const int* __restrict__ f_mask,
    const float* __restrict__ centers,
    u64* __restrict__ pat64, u64* __restrict__ care64,
    float* __restrict__ kk, float* __restrict__ vv,
    u64* __restrict__ code64, float* __restrict__ cali) {
  int blk = blockIdx.x;
  int tid = threadIdx.x;
  __shared__ float sh[D1];   // rep[] for prep, xs[] for codes

  if (blk < Fv * Cv) {
    // ---------------- prep ----------------
    int fc = blk;
    int f = fc >> 10;
    if (tid < Dv) sh[tid] = pat_rep[fc * Dv + tid];
    if (tid == Dv) {
      float p = pos_cnt[fc], n = neg_cnt[fc];
      sh[Dv] = p / (p + n + 1e-6f);
    }
    if (tid == 63) {
      u64 pp = 0, cm = 0;
      const int* prow = pat + fc * Fv;
      #pragma unroll
      for (int ff = 0; ff < Fv; ff++) {
        int pv = prow[ff];
        pp |= ((u64)(pv & 0xFF)) << (8 * ff);
        if (pv != 0) cm |= 0xFFull << (8 * ff);
      }
      pat64[fc] = pp;
      care64[fc] = cm;
    }
    __syncthreads();
    if (tid < Dv) {
      const float* w = W_k + (f * Dv + tid) * D1;
      float s = b_k[f * Dv + tid];
      #pragma unroll
      for (int j = 0; j < D1; j++) s += w[j] * sh[j];
      kk[fc * Dv + tid] = s;
    }
    if (tid < D1) {
      const float* w = W_v + (f * D1 + tid) * D1;
      float s = b_v[f * D1 + tid];
      #pragma unroll
      for (int j = 0; j < D1; j++) s += w[j] * sh[j];
      vv[fc * D1 + tid] = s;
    }
  } else if (blk < Fv * Cv + Bv * Tv) {
    // ---------------- codes ----------------
    int bt = blk - Fv * Cv;
    int lane = tid;   // center k
    u64 code = 0;
    for (int ff = 0; ff < Fv; ff++) {
      if (lane < Dv) sh[lane] = tdata[(bt * Fv + ff) * Dv + lane];
      __syncthreads();
      float xx = 0.0f;
      #pragma unroll
      for (int j = 0; j < Dv; j++) xx += sh[j] * sh[j];
      const float* cen = centers + (ff * Kv + lane) * Dv;
      float dot = 0.0f, cc = 0.0f;
      #pragma unroll
      for (int j = 0; j < Dv; j++) { float cv = cen[j]; dot += sh[j] * cv; cc += cv * cv; }
      float d = xx - 2.0f * dot + cc;
      int kidx = lane;
      #pragma unroll
      for (int off = 32; off >= 1; off >>= 1) {
        float od = __shfl_xor(d, off, 64);
        int ok = __shfl_xor(kidx, off, 64);
        if (od < d || (od == d && ok < kidx)) { d = od; kidx = ok; }
      }
      int m = f_mask[bt * Fv + ff];
      int codev = (m != 0) ? (kidx + 2) : 1;
      code |= ((u64)codev) << (8 * ff);
      __syncthreads();
    }
    if (lane == 0) code64[bt] = code;
  } else {
    // ---------------- zero cali (atomics target in K2) ----------------
    #pragma unroll
    for (int i = 0; i < (Bv * Ov) / 64; i++) cali[tid + 64 * i] = 0.0f;
  }
}

// ---------------------------------------------------------------------------
// K2: per (f,b) block — match scan, softmax, a_all write, sparse PV,
// srep write, and atomic cali partial-dot accumulation.
// 256 threads, 4 patterns per thread.
// ---------------------------------------------------------------------------
__global__ __launch_bounds__(256) void k2_attn(
    const float* __restrict__ tdata, const int* __restrict__ f_mask,
    const float* __restrict__ W_q, const float* __restrict__ b_q,
    const float* __restrict__ b_v, const float* __restrict__ W_pred,
    const u64* __restrict__ code64, const u64* __restrict__ pat64,
    const u64* __restrict__ care64,
    const float* __restrict__ kk, const float* __restrict__ vv,
    float* __restrict__ a_out, float* __restrict__ srep_out,
    float* __restrict__ cali) {
  int b = blockIdx.x, f = blockIdx.y;
  int tid = threadIdx.x;
  __shared__ float qs[Dv], iqs[Dv];
  __shared__ u64 cds[Tv];
  __shared__ float redm[4], reds[4];
  __shared__ float vsum[D1];
  __shared__ int fm_sh;

  if (tid < Tv) cds[tid] = code64[b * Tv + tid];
  if (tid < Dv) qs[tid] = tdata[((b * Tv + (Tv - 1)) * Fv + f) * Dv + tid];
  if (tid < D1) vsum[tid] = 0.0f;
  if (tid == 64) {
    int any = 0;
    #pragma unroll
    for (int t = 0; t < Tv; t++) any |= f_mask[(b * Tv + t) * Fv + f];
    fm_sh = (any != 0);
  }
  __syncthreads();
  if (tid < Dv) {
    const float* w = W_q + (f * Dv + tid) * Dv;
    float s = b_q[f * Dv + tid];
    #pragma unroll
    for (int j = 0; j < Dv; j++) s += w[j] * qs[j];
    iqs[tid] = s;
  }
  __syncthreads();

  int c0 = tid * 4;
  const u64* p64 = pat64 + f * Cv;
  const u64* c64 = care64 + f * Cv;
  bool matchv[4];
  float ev[4];
  float local_max = -INFINITY;
  #pragma unroll
  for (int j = 0; j < 4; j++) {
    int c = c0 + j;
    u64 pp = p64[c], cm = c64[c];
    bool m = false;
    #pragma unroll
    for (int t = 0; t < Tv; t++) m = m || (((cds[t] ^ pp) & cm) == 0ull);
    matchv[j] = m;
    ev[j] = 0.0f;
    if (m) {
      const float* krow = kk + (f * Cv + c) * Dv;
      float s = 0.0f;
      #pragma unroll
      for (int jj = 0; jj < Dv; jj++) s += krow[jj] * iqs[jj];
      ev[j] = s;
      local_max = fmaxf(local_max, s);
    }
  }

  // block max of matched e (stays -inf if no match in whole block)
  float mx = local_max;
  #pragma unroll
  for (int off = 32; off >= 1; off >>= 1) mx = fmaxf(mx, __shfl_xor(mx, off, 64));
  if ((tid & 63) == 0) redm[tid >> 6] = mx;
  __syncthreads();
  float bmax = fmaxf(fmaxf(redm[0], redm[1]), fmaxf(redm[2], redm[3]));
  bool nomatch = (bmax == -INFINITY);

  float av[4] = {0.f, 0.f, 0.f, 0.f};
  float lsum = 0.0f;
  if (!nomatch) {
    #pragma unroll
    for (int j = 0; j < 4; j++) {
      if (matchv[j]) { av[j] = expf(ev[j] - bmax); lsum += av[j]; }
    }
  }
  float ss = lsum;
  #pragma unroll
  for (int off = 32; off >= 1; off >>= 1) ss += __shfl_xor(ss, off, 64);
  if ((tid & 63) == 0) reds[tid >> 6] = ss;
  __syncthreads();
  float Z = reds[0] + reds[1] + reds[2] + reds[3];

  float4 aq;
  if (nomatch) {
    const float u = 1.0f / 1024.0f;
    aq = make_float4(u, u, u, u);
  } else {
    float a0 = av[0] / Z, a1 = av[1] / Z, a2 = av[2] / Z, a3 = av[3] / Z;
    aq = make_float4(a0, a1, a2, a3);
    // sparse PV accumulation (a is exactly 0 for unmatched)
    float aa[4] = {a0, a1, a2, a3};
    #pragma unroll
    for (int j = 0; j < 4; j++) {
      if (matchv[j] && aa[j] != 0.0f) {
        const float* vrow = vv + (f * Cv + c0 + j) * D1;
        for (int d = 0; d < D1; d++) atomicAdd(&vsum[d], aa[j] * vrow[d]);
      }
    }
  }
  // a_all write: row (f,b), contiguous 1024 floats, float4 per thread
  ((float4*)(a_out + (size_t)(f * Bv + b) * Cv))[tid] = aq;

  __syncthreads();
  if (tid < D1) {
    float vd = nomatch ? b_v[f * D1 + tid] : vsum[tid];
    vd = fm_sh ? vd : 0.0f;
    srep_out[(b * Fv + f) * D1 + tid] = vd;
    vsum[tid] = vd;   // reuse as the srep slice for the cali partial dot
  }
  __syncthreads();
  if (tid < Ov) {
    const float* w = W_pred + tid * (Fv * D1) + f * D1;
    float acc = 0.0f;
    #pragma unroll
    for (int d = 0; d < D1; d++) acc += vsum[d] * w[d];
    atomicAdd(&cali[b * Ov + tid], acc);
  }
}

extern "C" void kernel_launch(void* const* d_in, const int* in_sizes, int n_in,
                              void* d_out, int out_size, void* d_ws, size_t ws_size,
                              hipStream_t stream) {
  const float* tdata   = (const float*)d_in[0];
  const int*   f_mask  = (const int*)d_in[1];
  const float* centers = (const float*)d_in[2];
  const int*   pat     = (const int*)d_in[3];
  const float* pat_rep = (const float*)d_in[4];
  const float* pos_cnt = (const float*)d_in[5];
  const float* neg_cnt = (const float*)d_in[6];
  const float* W_q     = (const float*)d_in[7];
  const float* b_q     = (const float*)d_in[8];
  const float* W_k     = (const float*)d_in[9];
  const float* b_k     = (const float*)d_in[10];
  const float* W_v     = (const float*)d_in[11];
  const float* b_v     = (const float*)d_in[12];
  const float* W_pred  = (const float*)d_in[13];

  float* out = (float*)d_out;
  float* cali = out;                                        // Bv*Ov
  float* a_all = out + (Bv * Ov);                           // Fv*Bv*Cv
  float* srep = out + (Bv * Ov) + (Fv * (size_t)Bv * Cv);   // Bv*Fv*D1

  char* ws = (char*)d_ws;
  u64*   code64 = (u64*)(ws);                               // Bv*Tv
  u64*   pat64  = (u64*)(ws + 32768);                       // Fv*Cv
  u64*   care64 = (u64*)(ws + 98304);                       // Fv*Cv
  float* kk     = (float*)(ws + 163840);                    // Fv*Cv*Dv
  float* vv     = (float*)(ws + 163840 + Fv * Cv * Dv * 4); // Fv*Cv*D1

  k1_prep_codes<<<Fv * Cv + Bv * Tv + 1, 64, 0, stream>>>(
      pat, pat_rep, pos_cnt, neg_cnt, W_k, b_k, W_v, b_v,
      tdata, f_mask, centers,
      pat64, care64, kk, vv, code64, cali);
  k2_attn<<<dim3(Bv, Fv), 256, 0, stream>>>(
      tdata, f_mask, W_q, b_q, b_v, W_pred,
      code64, pat64, care64, kk, vv,
      a_all, srep, cali);
}

// Round 3
// 107.064 us; speedup vs baseline: 1.4366x; 1.3162x over previous
//
#include <hip/hip_runtime.h>
#include <math.h>

#define Bv 256
#define Tv 16
#define Fv 8
#define Dv 32
#define Kv 64
#define Cv 1024
#define Ov 2
#define D1 33   // D+1

typedef unsigned long long u64;
typedef unsigned char u8;

// ---------------------------------------------------------------------------
// K1, 256 threads/block:
//   blocks [0,128)   : codes. blk=(ff,g); thread handles bt=g*256+tid.
//                      k is wave-uniform -> centers loads are broadcast
//                      (1 line/inst), x row lives in registers (own line).
//                      Writes one code byte per (bt,ff) (distinct addresses).
//   blocks [128,160) : pattern pack -> pat64/care64 (thread = one fc).
//   block  160       : zero cali (atomic target in K2).
// ---------------------------------------------------------------------------
__global__ __launch_bounds__(256) void k1(
    const float* __restrict__ tdata, const int* __restrict__ f_mask,
    const float* __restrict__ centers, const int* __restrict__ pat,
    u8* __restrict__ cbytes, u64* __restrict__ pat64, u64* __restrict__ care64,
    float* __restrict__ cali) {
  int blk = blockIdx.x, tid = threadIdx.x;
  if (blk < 128) {
    int ff = blk >> 4;
    int bt = ((blk & 15) << 8) + tid;
    __shared__ float ccs[Kv];
    if (tid < Kv) {   // wave 0: ||center_k||^2 (one-time small gather)
      const float* cr = centers + (ff * Kv + tid) * Dv;
      float s = 0.f;
      #pragma unroll
      for (int j = 0; j < Dv; j++) { float cv = cr[j]; s += cv * cv; }
      ccs[tid] = s;
    }
    const float4* xr = (const float4*)(tdata + (size_t)(bt * Fv + ff) * Dv);
    float4 xq[8];
    #pragma unroll
    for (int i = 0; i < 8; i++) xq[i] = xr[i];
    __syncthreads();
    // argmin_k (||x||^2 - 2 x.c_k + cc_k); ||x||^2 dropped (argmin-invariant)
    float dmin = INFINITY; int kmin = 0;
    const float4* cb = (const float4*)(centers + ff * Kv * Dv);
    #pragma unroll 2
    for (int k = 0; k < Kv; k++) {
      const float4* cr = cb + k * 8;   // wave-uniform address -> broadcast
      float4 dv = make_float4(0.f, 0.f, 0.f, 0.f);
      #pragma unroll
      for (int i = 0; i < 8; i++) {
        float4 cq = cr[i];
        dv.x += xq[i].x * cq.x; dv.y += xq[i].y * cq.y;
        dv.z += xq[i].z * cq.z; dv.w += xq[i].w * cq.w;
      }
      float dot = (dv.x + dv.y) + (dv.z + dv.w);
      float d = ccs[k] - 2.0f * dot;
      if (d < dmin) { dmin = d; kmin = k; }   // strict < : first-index tie ✓
    }
    int m = f_mask[bt * Fv + ff];
    cbytes[bt * Fv + ff] = (u8)(m != 0 ? kmin + 2 : 1);
  } else if (blk < 160) {
    int fc = ((blk - 128) << 8) + tid;
    const int* pr = pat + fc * Fv;
    u64 pp = 0, cm = 0;
    #pragma unroll
    for (int ff = 0; ff < Fv; ff++) {
      int pv = pr[ff];
      pp |= ((u64)(pv & 0xFF)) << (8 * ff);
      if (pv != 0) cm |= 0xFFull << (8 * ff);
    }
    pat64[fc] = pp;
    care64[fc] = cm;
  } else {
    cali[tid] = 0.f;
    cali[tid + 256] = 0.f;
  }
}

// ---------------------------------------------------------------------------
// K2: per (b,f) block, 256 threads, 4 patterns/thread.
// Common path (no match in block — statistically always): a = 1/1024
// uniform, srep = fm ? b_v : 0, cali atomic partial dot. No tdata/W reads.
// Rare path: z = Wk^T iq trick for e; w = sum a_c rep_c then v = Wv w + bv.
// ---------------------------------------------------------------------------
__global__ __launch_bounds__(256) void k2(
    const float* __restrict__ tdata, const int* __restrict__ f_mask,
    const float* __restrict__ W_q, const float* __restrict__ b_q,
    const float* __restrict__ W_k, const float* __restrict__ b_k,
    const float* __restrict__ W_v, const float* __restrict__ b_v,
    const float* __restrict__ W_pred,
    const float* __restrict__ pat_rep, const float* __restrict__ pos_cnt,
    const float* __restrict__ neg_cnt,
    const u64* __restrict__ code64, const u64* __restrict__ pat64,
    const u64* __restrict__ care64,
    float* __restrict__ a_out, float* __restrict__ srep_out,
    float* __restrict__ cali) {
  int b = blockIdx.x, f = blockIdx.y, tid = threadIdx.x;
  __shared__ u64 cds[Tv];
  __shared__ int fmv[Tv];
  __shared__ int fm_sh;
  __shared__ int anyf[4];
  __shared__ float vsum[D1];
  __shared__ float qs[Dv], iqs[Dv], zs[D1 + 1];
  __shared__ float redm[4], reds[4];

  if (tid < Tv) cds[tid] = code64[b * Tv + tid];
  if (tid >= 32 && tid < 32 + Tv) fmv[tid - 32] = f_mask[(b * Tv + (tid - 32)) * Fv + f];
  if (tid < D1) vsum[tid] = 0.f;
  if (tid >= 60 && tid < 64) anyf[tid - 60] = 0;
  __syncthreads();
  if (tid == 0) {
    int a = 0;
    #pragma unroll
    for (int t = 0; t < Tv; t++) a |= fmv[t];
    fm_sh = (a != 0);
  }

  int c0 = tid * 4;
  const u64* p64 = pat64 + f * Cv;
  const u64* c64 = care64 + f * Cv;
  u64 pp[4], cm[4];
  #pragma unroll
  for (int j = 0; j < 4; j++) { pp[j] = p64[c0 + j]; cm[j] = c64[c0 + j]; }
  bool mt[4];
  #pragma unroll
  for (int j = 0; j < 4; j++) {
    bool m = false;
    #pragma unroll
    for (int t = 0; t < Tv; t++) m = m || (((cds[t] ^ pp[j]) & cm[j]) == 0ull);
    mt[j] = m;
  }
  bool lany = mt[0] || mt[1] || mt[2] || mt[3];
  if (__any((int)lany) && (tid & 63) == 0) anyf[tid >> 6] = 1;
  __syncthreads();
  bool anym = (anyf[0] | anyf[1] | anyf[2] | anyf[3]) != 0;

  float4* arow = (float4*)(a_out + (size_t)(f * Bv + b) * Cv);

  if (!anym) {
    // ---------------- common (degenerate) path ----------------
    const float u = 1.0f / 1024.0f;
    arow[tid] = make_float4(u, u, u, u);
    if (tid < D1) {
      float vd = fm_sh ? b_v[f * D1 + tid] : 0.f;
      srep_out[(b * Fv + f) * D1 + tid] = vd;
      vsum[tid] = vd;
    }
    __syncthreads();
    if (tid < Ov) {
      const float* w = W_pred + tid * (Fv * D1) + f * D1;
      float acc = 0.f;
      #pragma unroll
      for (int j = 0; j < D1; j++) acc += vsum[j] * w[j];
      atomicAdd(&cali[b * Ov + tid], acc);
    }
    return;
  }

  // ---------------- rare full path (correctness only) ----------------
  if (tid < Dv) qs[tid] = tdata[((b * Tv + (Tv - 1)) * Fv + f) * Dv + tid];
  __syncthreads();
  if (tid < Dv) {
    const float* w = W_q + (f * Dv + tid) * Dv;
    float s = b_q[f * Dv + tid];
    #pragma unroll
    for (int j = 0; j < Dv; j++) s += w[j] * qs[j];
    iqs[tid] = s;
  }
  __syncthreads();
  if (tid < D1) {
    float s = 0.f;
    #pragma unroll
    for (int i = 0; i < Dv; i++) s += W_k[(f * Dv + i) * D1 + tid] * iqs[i];
    zs[tid] = s;
  }
  if (tid == D1) {
    float s = 0.f;
    #pragma unroll
    for (int i = 0; i < Dv; i++) s += b_k[f * Dv + i] * iqs[i];
    zs[D1] = s;
  }
  __syncthreads();

  float ev[4];
  float lmax = -INFINITY;
  #pragma unroll
  for (int j = 0; j < 4; j++) {
    ev[j] = 0.f;
    if (mt[j]) {
      int c = c0 + j;
      const float* rp = pat_rep + (size_t)(f * Cv + c) * Dv;
      float p = pos_cnt[f * Cv + c], n = neg_cnt[f * Cv + c];
      float r = p / (p + n + 1e-6f);
      float s = zs[D1] + r * zs[Dv];
      for (int jj = 0; jj < Dv; jj++) s += rp[jj] * zs[jj];
      ev[j] = s;
      lmax = fmaxf(lmax, s);
    }
  }
  float mx = lmax;
  #pragma unroll
  for (int off = 32; off >= 1; off >>= 1) mx = fmaxf(mx, __shfl_xor(mx, off, 64));
  if ((tid & 63) == 0) redm[tid >> 6] = mx;
  __syncthreads();
  float bmax = fmaxf(fmaxf(redm[0], redm[1]), fmaxf(redm[2], redm[3]));

  float av[4] = {0.f, 0.f, 0.f, 0.f};
  float ls = 0.f;
  #pragma unroll
  for (int j = 0; j < 4; j++) {
    if (mt[j]) { av[j] = expf(ev[j] - bmax); ls += av[j]; }
  }
  float ss = ls;
  #pragma unroll
  for (int off = 32; off >= 1; off >>= 1) ss += __shfl_xor(ss, off, 64);
  if ((tid & 63) == 0) reds[tid >> 6] = ss;
  __syncthreads();
  float Z = reds[0] + reds[1] + reds[2] + reds[3];

  float4 aq = make_float4(av[0] / Z, av[1] / Z, av[2] / Z, av[3] / Z);
  arow[tid] = aq;

  #pragma unroll
  for (int j = 0; j < 4; j++) {
    if (mt[j] && av[j] != 0.f) {
      float a = av[j] / Z;
      int c = c0 + j;
      const float* rp = pat_rep + (size_t)(f * Cv + c) * Dv;
      float p = pos_cnt[f * Cv + c], n = neg_cnt[f * Cv + c];
      float r = p / (p + n + 1e-6f);
      for (int jj = 0; jj < Dv; jj++) atomicAdd(&vsum[jj], a * rp[jj]);
      atomicAdd(&vsum[Dv], a * r);
    }
  }
  __syncthreads();
  float vreg = 0.f;
  if (tid < D1) {
    float s = b_v[f * D1 + tid];
    const float* w = W_v + (f * D1 + tid) * D1;
    for (int j = 0; j < D1; j++) s += w[j] * vsum[j];
    vreg = s;
  }
  __syncthreads();
  if (tid < D1) {
    float vd = fm_sh ? vreg : 0.f;
    srep_out[(b * Fv + f) * D1 + tid] = vd;
    vsum[tid] = vd;
  }
  __syncthreads();
  if (tid < Ov) {
    const float* w = W_pred + tid * (Fv * D1) + f * D1;
    float acc = 0.f;
    #pragma unroll
    for (int j = 0; j < D1; j++) acc += vsum[j] * w[j];
    atomicAdd(&cali[b * Ov + tid], acc);
  }
}

extern "C" void kernel_launch(void* const* d_in, const int* in_sizes, int n_in,
                              void* d_out, int out_size, void* d_ws, size_t ws_size,
                              hipStream_t stream) {
  const float* tdata   = (const float*)d_in[0];
  const int*   f_mask  = (const int*)d_in[1];
  const float* centers = (const float*)d_in[2];
  const int*   pat     = (const int*)d_in[3];
  const float* pat_rep = (const float*)d_in[4];
  const float* pos_cnt = (const float*)d_in[5];
  const float* neg_cnt = (const float*)d_in[6];
  const float* W_q     = (const float*)d_in[7];
  const float* b_q     = (const float*)d_in[8];
  const float* W_k     = (const float*)d_in[9];
  const float* b_k     = (const float*)d_in[10];
  const float* W_v     = (const float*)d_in[11];
  const float* b_v     = (const float*)d_in[12];
  const float* W_pred  = (const float*)d_in[13];

  float* out = (float*)d_out;
  float* cali = out;                                        // Bv*Ov
  float* a_all = out + (Bv * Ov);                           // Fv*Bv*Cv
  float* srep = out + (Bv * Ov) + (Fv * (size_t)Bv * Cv);   // Bv*Fv*D1

  char* ws = (char*)d_ws;
  u8*  cbytes = (u8*)(ws);              // Bv*Tv*Fv bytes = code64 view
  u64* code64 = (u64*)(ws);
  u64* pat64  = (u64*)(ws + 32768);     // Fv*Cv
  u64* care64 = (u64*)(ws + 98304);     // Fv*Cv

  k1<<<161, 256, 0, stream>>>(tdata, f_mask, centers, pat,
                              cbytes, pat64, care64, cali);
  k2<<<dim3(Bv, Fv), 256, 0, stream>>>(tdata, f_mask, W_q, b_q, W_k, b_k,
                                       W_v, b_v, W_pred,
                                       pat_rep, pos_cnt, neg_cnt,
                                       code64, pat64, care64,
                                       a_all, srep, cali);
}